// Round 8
// baseline (105147.644 us; speedup 1.0000x reference)
//
#include <hip/hip_runtime.h>
#include <math.h>

#define NN    2048
#define DE    128
#define DH    256
#define NE    65536
#define NBLK  128      // outer blocks of 16 rows
#define BS    16
#define OUTER_SWEEPS 8
#define LSW_EARLY 3    // local sweeps, early outer sweeps (rate only, not accuracy)
#define LSW_LATE  6    // local sweeps, last two outer sweeps (polish)

// rotation params — identical formula to all passing versions
__device__ __forceinline__ void jrot2(float app, float aqq, float apq, float& c, float& s) {
  if (fabsf(apq) <= 1e-30f) { c = 1.f; s = 0.f; return; }
  float tau = (aqq - app) / (2.f * apq);
  float den = fabsf(tau) + sqrtf(1.f + tau * tau);
  float t = ((tau >= 0.f) ? 1.f : -1.f) / den;
  c = 1.f / sqrtf(1.f + t * t);
  s = t * c;
}

// round-robin (circle method) pairing of 128 blocks; round rr in [0,127)
__device__ __forceinline__ void pair_of(int rr, int i, int& bp, int& bq) {
  int p, q;
  if (i == 0) { p = NBLK - 1; q = rr % (NBLK - 1); }
  else { p = (rr + i) % (NBLK - 1); q = (rr - i + (NBLK - 1)) % (NBLK - 1); }
  bp = min(p, q); bq = max(p, q);
}

// inverse: which pair index holds 16-block g in round rr
__device__ __forceinline__ int inv_pair(int rr, int g) {
  if (g == NBLK - 1) return 0;
  if (g == rr % (NBLK - 1)) return 0;
  int d = (g - rr) % (NBLK - 1); if (d < 0) d += (NBLK - 1);
  return (d <= NBLK / 2 - 1) ? d : (NBLK - 1 - d);
}

// local 32x32 chess-tournament pairing: 16 pairs over 31 rounds, r2 in [0,31)
// identical values to the previous LDS-table version (%31 arithmetic, branch-free)
__device__ __forceinline__ void lpair(int r2, int k, int& pp, int& qq) {
  int aa, bb;
  if (k == 0) { aa = 31; bb = r2; }
  else {
    aa = r2 + k; if (aa >= 31) aa -= 31;
    bb = r2 - k; if (bb < 0) bb += 31;
  }
  pp = min(aa, bb); qq = max(aa, bb);
}

// ---------------- fused per-round kernel ----------------
// blocks [0,64):        solve U_{r+1} from Ain (state r-1) with on-the-fly U_r update
// blocks [64,4160):     A-apply i<=j: Aout(i,j) = Ui^T Ain(i,j) Uj, mirror to (j,i)
// blocks [4160,8256):   V-apply: V(:,Sj) = V(:,Sj) Uj   (in place)
__global__ __launch_bounds__(64) void jacobi_round(
    const float* __restrict__ Ain, float* __restrict__ Aout,
    float* __restrict__ V,
    const float* __restrict__ Ucur, int rr_cur,
    float* __restrict__ Unext, int rr_next, int lsw)
{
  __shared__ float L0[32][36];   // AA / SA / Tvt / S-pong
  __shared__ float L1[32][36];   // U1t
  __shared__ float L2[32][36];   // U2t / U2n / U2v
  __shared__ float L3[32][36];   // Tt
  __shared__ float L4[32][36];   // S-ping
  __shared__ float L5[32][36];   // Ut
  const int tid = threadIdx.x;
  const int b = blockIdx.x;

  if (b < 64) {
    // ================= SOLVE =================
    if (rr_next < 0) return;
    int pP, pQ; pair_of(rr_next, b, pP, pQ);   // pP < pQ
    {   // Ut = I
      int a = tid >> 1, ch = (tid & 1) * 16;
      #pragma unroll
      for (int q = 0; q < 4; ++q) {
        int c4 = ch + q * 4;
        L5[a][c4]     = (a == c4)     ? 1.f : 0.f;
        L5[a][c4 + 1] = (a == c4 + 1) ? 1.f : 0.f;
        L5[a][c4 + 2] = (a == c4 + 2) ? 1.f : 0.f;
        L5[a][c4 + 3] = (a == c4 + 3) ? 1.f : 0.f;
      }
    }
    if (rr_cur < 0) {
      // direct load of the 32x32 [pP pP; pP pQ; ...] from Ain
      int a = tid >> 1, ch = (tid & 1) * 16;
      int gr = (a < BS) ? (pP * BS + a) : (pQ * BS + a - BS);
      #pragma unroll
      for (int q = 0; q < 4; ++q) {
        int c4 = ch + q * 4;
        int gc = (c4 < BS) ? (pP * BS + c4) : (pQ * BS + c4 - BS);
        *(float4*)&L4[a][c4] = *(const float4*)(Ain + ((size_t)gr << 11) + gc);
      }
      __syncthreads();
    } else {
      const int i1 = inv_pair(rr_cur, pP), i2 = inv_pair(rr_cur, pQ);
      int bp1, bq1; pair_of(rr_cur, i1, bp1, bq1);
      int bp2, bq2; pair_of(rr_cur, i2, bp2, bq2);
      const int o1 = (pP == bp1) ? 0 : 16;
      const int o2 = (pQ == bp2) ? 0 : 16;
      {   // load U1t, U2t (transposed storage as written by previous solve)
        int a = tid >> 1, ch = (tid & 1) * 16;
        #pragma unroll
        for (int q = 0; q < 4; ++q) {
          int c4 = ch + q * 4;
          *(float4*)&L1[a][c4] = *(const float4*)(Ucur + ((size_t)i1 << 10) + (a << 5) + c4);
          *(float4*)&L2[a][c4] = *(const float4*)(Ucur + ((size_t)i2 << 10) + (a << 5) + c4);
        }
      }
      // three supertiles: (i1,i1)->S[0:16,0:16]; (i1,i2)->S[0:16,16:32]+mirror; (i2,i2)->S[16:,16:]
      #pragma unroll
      for (int t3 = 0; t3 < 3; ++t3) {
        const int bpa = (t3 == 2) ? bp2 : bp1, bqa = (t3 == 2) ? bq2 : bq1;
        const int bpb = (t3 == 0) ? bp1 : bp2, bqb = (t3 == 0) ? bq1 : bq2;
        const float (*Ua)[36] = (t3 == 2) ? L2 : L1;
        const float (*Ub)[36] = (t3 == 0) ? L1 : L2;
        const int oa = (t3 == 2) ? o2 : o1;
        const int ob = (t3 == 0) ? o1 : o2;
        const int dr = (t3 == 2) ? 16 : 0;
        const int dc = (t3 == 0) ? 0 : 16;
        {   // load supertile
          int a = tid >> 1, ch = (tid & 1) * 16;
          int gr = (a < BS) ? (bpa * BS + a) : (bqa * BS + a - BS);
          #pragma unroll
          for (int q = 0; q < 4; ++q) {
            int c4 = ch + q * 4;
            int gc = (c4 < BS) ? (bpb * BS + c4) : (bqb * BS + c4 - BS);
            *(float4*)&L0[a][c4] = *(const float4*)(Ain + ((size_t)gr << 11) + gc);
          }
        }
        __syncthreads();
        {   // T1(16x32) = Ua(:,oa:oa+16)^T * AA
          int rT = tid >> 2, cb = (tid & 3) * 8;
          float t1[8] = {};
          for (int k = 0; k < 32; ++k) {
            float u = Ua[oa + rT][k];
            #pragma unroll
            for (int c = 0; c < 8; ++c) t1[c] += u * L0[k][cb + c];
          }
          #pragma unroll
          for (int c = 0; c < 8; ++c) L3[rT][cb + c] = t1[c];
        }
        __syncthreads();
        {   // Q(16x16) = T1 * Ub(:,ob:ob+16)
          int rQ = tid >> 2, c0 = (tid & 3) * 4;
          float qv[4] = {};
          for (int k = 0; k < 32; ++k) {
            float tv = L3[rQ][k];
            #pragma unroll
            for (int c = 0; c < 4; ++c) qv[c] += tv * Ub[ob + c0 + c][k];
          }
          #pragma unroll
          for (int c = 0; c < 4; ++c) {
            L4[dr + rQ][dc + c0 + c] = qv[c];
            if (t3 == 1) L4[dc + c0 + c][dr + rQ] = qv[c];   // symmetric mirror
          }
        }
        __syncthreads();
      }
    }
    // -------- local Jacobi on S (ping-pong L4/L0), accumulate Ut (L5) --------
    // v7: rotations live in REGISTERS (all lanes compute jrot for pair tid&15 —
    // 4-way redundant, broadcast LDS reads) and move via __shfl (one bpermute
    // hop) instead of the rc/rs LDS round-trip + extra barrier. Same inputs,
    // same formula, same schedule -> bitwise-identical trajectory to R6.
    float (*Sc)[36] = L4;     // current
    float (*Sn)[36] = L0;     // next (L0 is free after reconstruction)
    for (int sw = 0; sw < lsw; ++sw) {
      {   // convergence check (wave-uniform)
        float off2 = 0.f, d2 = 0.f;
        int a = tid >> 1, ch = (tid & 1) * 16;
        for (int c = ch; c < ch + 16; ++c) {
          float v = Sc[a][c];
          if (c == a) d2 += v * v; else off2 += v * v;
        }
        #pragma unroll
        for (int o = 1; o < 64; o <<= 1) {
          off2 += __shfl_xor(off2, o, 64);
          d2   += __shfl_xor(d2, o, 64);
        }
        if (off2 <= 1e-11f * d2) break;
      }
      for (int r2 = 0; r2 < 31; ++r2) {
        // my pair (m = tid&15) and its rotation, in registers
        int myP, myQ; lpair(r2, tid & 15, myP, myQ);
        float c_reg, s_reg;
        jrot2(Sc[myP][myP], Sc[myQ][myQ], Sc[myP][myQ], c_reg, s_reg);
        // fused two-sided update Sn = J^T Sc J — disjoint pairs, one LDS phase.
        // col rotation (m = tid&15) is this thread's own register; row rotation via shfl.
        #pragma unroll
        for (int it = 0; it < 4; ++it) {
          int t = tid + it * 64;
          int k = t >> 4;
          int P, Q; lpair(r2, k, P, Q);
          float ck = __shfl(c_reg, k, 64), sk = __shfl(s_reg, k, 64);
          float cm = c_reg, sm = s_reg;
          int Cp = myP, Cq = myQ;
          float a0 = Sc[P][Cp], b0 = Sc[P][Cq];
          float c0 = Sc[Q][Cp], d0 = Sc[Q][Cq];
          float r0p = ck * a0 - sk * c0;   // row-rotated, col Cp
          float r0q = ck * b0 - sk * d0;   // row-rotated, col Cq
          float r1p = sk * a0 + ck * c0;
          float r1q = sk * b0 + ck * d0;
          Sn[P][Cp] = cm * r0p - sm * r0q;
          Sn[P][Cq] = sm * r0p + cm * r0q;
          Sn[Q][Cp] = cm * r1p - sm * r1q;
          Sn[Q][Cq] = sm * r1p + cm * r1q;
        }
        #pragma unroll
        for (int it = 0; it < 2; ++it) {   // Ut row phase (b128, in place, disjoint rows)
          int t = tid + it * 64;
          int k = t >> 3, q4 = (t & 7) << 2;
          int P, Q; lpair(r2, k, P, Q);
          float c = __shfl(c_reg, k, 64), s = __shfl(s_reg, k, 64);
          float4 xp = *(const float4*)&L5[P][q4];
          float4 xq = *(const float4*)&L5[Q][q4];
          *(float4*)&L5[P][q4] = make_float4(c*xp.x - s*xq.x, c*xp.y - s*xq.y,
                                             c*xp.z - s*xq.z, c*xp.w - s*xq.w);
          *(float4*)&L5[Q][q4] = make_float4(s*xp.x + c*xq.x, s*xp.y + c*xq.y,
                                             s*xp.z + c*xq.z, s*xp.w + c*xq.w);
        }
        __syncthreads();
        float (*tp)[36] = Sc; Sc = Sn; Sn = tp;   // swap ping-pong
      }
    }
    {   // write Ut (transposed layout: Unext[b][r*32+k] = U[k][r])
      int r = tid >> 1, ch = (tid & 1) * 16;
      #pragma unroll
      for (int q = 0; q < 4; ++q) {
        int c4 = ch + q * 4;
        *(float4*)(Unext + ((size_t)b << 10) + (r << 5) + c4) = *(const float4*)&L5[r][c4];
      }
    }
  } else if (b < 64 + 4096) {
    // ================= A-APPLY (i<=j, ping-pong, mirror) =================
    const int idx = b - 64;
    const int i = idx >> 6, j = idx & 63;
    if (i > j) return;
    const int ta = tid >> 3, tb = tid & 7;
    int bpi, bqi; pair_of(rr_cur, i, bpi, bqi);
    int bpj, bqj; pair_of(rr_cur, j, bpj, bqj);
    {
      int a = tid >> 1, ch = (tid & 1) * 16;
      int gr = (a < BS) ? (bpi * BS + a) : (bqi * BS + a - BS);
      #pragma unroll
      for (int q = 0; q < 4; ++q) {
        int c4 = ch + q * 4;
        *(float4*)&L1[a][c4] = *(const float4*)(Ucur + ((size_t)i << 10) + (a << 5) + c4);
        const float4 u = *(const float4*)(Ucur + ((size_t)j << 10) + (a << 5) + c4);
        L2[c4][a] = u.x; L2[c4 + 1][a] = u.y; L2[c4 + 2][a] = u.z; L2[c4 + 3][a] = u.w;
        int gc = (c4 < BS) ? (bpj * BS + c4) : (bqj * BS + c4 - BS);
        *(float4*)&L0[a][c4] = *(const float4*)(Ain + ((size_t)gr << 11) + gc);
      }
    }
    __syncthreads();
    {   // stage 1: T = U1^T * SA, stored transposed into L3
      float acc[4][4] = {};
      for (int k4 = 0; k4 < 8; ++k4) {
        const float4 sa0 = *(const float4*)&L0[4 * k4 + 0][tb << 2];
        const float4 sa1 = *(const float4*)&L0[4 * k4 + 1][tb << 2];
        const float4 sa2 = *(const float4*)&L0[4 * k4 + 2][tb << 2];
        const float4 sa3 = *(const float4*)&L0[4 * k4 + 3][tb << 2];
        #pragma unroll
        for (int r = 0; r < 4; ++r) {
          const float4 u = *(const float4*)&L1[(ta << 2) + r][k4 << 2];
          acc[r][0] += u.x*sa0.x; acc[r][1] += u.x*sa0.y; acc[r][2] += u.x*sa0.z; acc[r][3] += u.x*sa0.w;
          acc[r][0] += u.y*sa1.x; acc[r][1] += u.y*sa1.y; acc[r][2] += u.y*sa1.z; acc[r][3] += u.y*sa1.w;
          acc[r][0] += u.z*sa2.x; acc[r][1] += u.z*sa2.y; acc[r][2] += u.z*sa2.z; acc[r][3] += u.z*sa2.w;
          acc[r][0] += u.w*sa3.x; acc[r][1] += u.w*sa3.y; acc[r][2] += u.w*sa3.z; acc[r][3] += u.w*sa3.w;
        }
      }
      #pragma unroll
      for (int r = 0; r < 4; ++r)
        #pragma unroll
        for (int c = 0; c < 4; ++c)
          L3[(tb << 2) + c][(ta << 2) + r] = acc[r][c];
    }
    __syncthreads();
    float o[4][4] = {};
    for (int k = 0; k < 32; ++k) {   // stage 2: Out = T * U2
      const float4 tv = *(const float4*)&L3[k][ta << 2];
      const float4 u  = *(const float4*)&L2[k][tb << 2];
      o[0][0]+=tv.x*u.x; o[0][1]+=tv.x*u.y; o[0][2]+=tv.x*u.z; o[0][3]+=tv.x*u.w;
      o[1][0]+=tv.y*u.x; o[1][1]+=tv.y*u.y; o[1][2]+=tv.y*u.z; o[1][3]+=tv.y*u.w;
      o[2][0]+=tv.z*u.x; o[2][1]+=tv.z*u.y; o[2][2]+=tv.z*u.z; o[2][3]+=tv.z*u.w;
      o[3][0]+=tv.w*u.x; o[3][1]+=tv.w*u.y; o[3][2]+=tv.w*u.z; o[3][3]+=tv.w*u.w;
    }
    #pragma unroll
    for (int r = 0; r < 4; ++r) {
      int a = (ta << 2) + r;
      int gr = (a < BS) ? (bpi * BS + a) : (bqi * BS + a - BS);
      int c4 = tb << 2;
      int gc = (c4 < BS) ? (bpj * BS + c4) : (bqj * BS + c4 - BS);
      *(float4*)(Aout + ((size_t)gr << 11) + gc) = make_float4(o[r][0], o[r][1], o[r][2], o[r][3]);
    }
    if (i != j) {   // mirror via LDS
      __syncthreads();
      #pragma unroll
      for (int r = 0; r < 4; ++r)
        #pragma unroll
        for (int c = 0; c < 4; ++c)
          L3[(tb << 2) + c][(ta << 2) + r] = o[r][c];
      __syncthreads();
      int a = tid >> 1, ch = (tid & 1) * 16;
      int gr2 = (a < BS) ? (bpj * BS + a) : (bqj * BS + a - BS);
      #pragma unroll
      for (int q = 0; q < 4; ++q) {
        int c4 = ch + q * 4;
        int gc2 = (c4 < BS) ? (bpi * BS + c4) : (bqi * BS + c4 - BS);
        *(float4*)(Aout + ((size_t)gr2 << 11) + gc2) = *(const float4*)&L3[a][c4];
      }
    }
  } else {
    // ================= V-APPLY (in place) =================
    const int vb = b - (64 + 4096);
    const int j = vb >> 6, rt = vb & 63;
    int bpj, bqj; pair_of(rr_cur, j, bpj, bqj);
    const int ta = tid >> 3, tb = tid & 7;
    {
      int a = tid >> 1, ch = (tid & 1) * 16;
      #pragma unroll
      for (int q = 0; q < 4; ++q) {
        int c4 = ch + q * 4;
        const float4 u = *(const float4*)(Ucur + ((size_t)j << 10) + (a << 5) + c4);
        L2[c4][a] = u.x; L2[c4 + 1][a] = u.y; L2[c4 + 2][a] = u.z; L2[c4 + 3][a] = u.w;
        int gc = (c4 < BS) ? (bpj * BS + c4) : (bqj * BS + c4 - BS);
        const float4 vv = *(const float4*)(V + ((size_t)(rt * 32 + a) << 11) + gc);
        L0[c4][a] = vv.x; L0[c4 + 1][a] = vv.y; L0[c4 + 2][a] = vv.z; L0[c4 + 3][a] = vv.w;
      }
    }
    __syncthreads();
    float o[4][4] = {};
    for (int k = 0; k < 32; ++k) {
      const float4 tv = *(const float4*)&L0[k][ta << 2];
      const float4 u  = *(const float4*)&L2[k][tb << 2];
      o[0][0]+=tv.x*u.x; o[0][1]+=tv.x*u.y; o[0][2]+=tv.x*u.z; o[0][3]+=tv.x*u.w;
      o[1][0]+=tv.y*u.x; o[1][1]+=tv.y*u.y; o[1][2]+=tv.y*u.z; o[1][3]+=tv.y*u.w;
      o[2][0]+=tv.z*u.x; o[2][1]+=tv.z*u.y; o[2][2]+=tv.z*u.z; o[2][3]+=tv.z*u.w;
      o[3][0]+=tv.w*u.x; o[3][1]+=tv.w*u.y; o[3][2]+=tv.w*u.z; o[3][3]+=tv.w*u.w;
    }
    #pragma unroll
    for (int r = 0; r < 4; ++r) {
      int c4 = tb << 2;
      int gc = (c4 < BS) ? (bpj * BS + c4) : (bqj * BS + c4 - BS);
      *(float4*)(V + ((size_t)(rt * 32 + (ta << 2) + r) << 11) + gc) =
          make_float4(o[r][0], o[r][1], o[r][2], o[r][3]);
    }
  }
}

// ---------------- graph / SAGE stage ----------------
__global__ void edge_deg_adj(const int* __restrict__ ei, const float* __restrict__ attr,
                             float* __restrict__ deg, float* __restrict__ Adense)
{
  int e = blockIdx.x * 256 + threadIdx.x;
  if (e >= NE) return;
  int s = ei[e], t = ei[NE + e];
  atomicAdd(&deg[t], 1.0f);
  Adense[((size_t)s << 11) + t] = attr[e];
}

__global__ void edge_agg(const int* __restrict__ ei, const float* __restrict__ attr,
                         const float* __restrict__ x, float* __restrict__ agg)
{
  int t0 = blockIdx.x * 256 + threadIdx.x;   // NE*32 items
  int e = t0 >> 5, c4 = (t0 & 31) * 4;
  int s = ei[e], t = ei[NE + e];
  float a = attr[e];
  const float4 xv = *(const float4*)(x + (size_t)s * DE + c4);
  atomicAdd(&agg[(size_t)t * DE + c4 + 0], xv.x * a);
  atomicAdd(&agg[(size_t)t * DE + c4 + 1], xv.y * a);
  atomicAdd(&agg[(size_t)t * DE + c4 + 2], xv.z * a);
  atomicAdd(&agg[(size_t)t * DE + c4 + 3], xv.w * a);
}

__global__ void div_agg(float* __restrict__ agg, const float* __restrict__ deg)
{
  int idx = blockIdx.x * 256 + threadIdx.x;  // NN*DE
  agg[idx] /= fmaxf(deg[idx >> 7], 1.0f);
}

__global__ __launch_bounds__(256) void gnn_h(const float* __restrict__ x, const float* __restrict__ agg,
        const float* __restrict__ wself, const float* __restrict__ wnbr,
        const float* __restrict__ bg, float* __restrict__ h)
{
  __shared__ float xs[16][DE];
  __shared__ float as[16][DE];
  int tx = threadIdx.x % 16, ty = threadIdx.x / 16;
  int i0 = blockIdx.y * 16, j = blockIdx.x * 16 + tx;
  for (int e = threadIdx.x; e < 16 * DE; e += 256) {
    int r = e >> 7, k = e & 127;
    xs[r][k] = x[(size_t)(i0 + r) * DE + k];
    as[r][k] = agg[(size_t)(i0 + r) * DE + k];
  }
  __syncthreads();
  float acc = bg[j];
  for (int k = 0; k < DE; ++k)
    acc += xs[ty][k] * wself[k * DH + j] + as[ty][k] * wnbr[k * DH + j];
  h[(size_t)(i0 + ty) * DH + j] = fmaxf(acc, 0.f);
}

__global__ void u_s_kernel(const float* __restrict__ h, const float* __restrict__ wlin,
                           float* __restrict__ u, float* __restrict__ srow)
{
  int i = blockIdx.x, j = threadIdx.x;      // 2048 blocks x 256
  float hv = h[(size_t)i * DH + j];
  float w = wlin[j];
  u[(size_t)i * DH + j] = hv * w;
  float p = hv * hv * w;
  for (int off = 32; off; off >>= 1) p += __shfl_down(p, off, 64);
  __shared__ float sw[4];
  if ((j & 63) == 0) sw[j >> 6] = p;
  __syncthreads();
  if (j == 0) srow[i] = sw[0] + sw[1] + sw[2] + sw[3];
}

// ---------------- generic 64x64x16 tiled fp32 GEMM ----------------
template<int TA, int TB, int MODE>
__global__ __launch_bounds__(256) void gemm64(int M, int Nn, int K,
            const float* __restrict__ A, int lda,
            const float* __restrict__ B, int ldb,
            float* __restrict__ Cc, int ldc,
            const float* __restrict__ svec, const float* __restrict__ bptr)
{
  __shared__ float As[16][65];
  __shared__ float Bs[16][65];
  const int tid = threadIdx.x;
  const int tx = tid % 16, ty = tid / 16;
  const int m0 = blockIdx.y * 64, n0 = blockIdx.x * 64;
  float acc[4][4] = {};
  for (int k0 = 0; k0 < K; k0 += 16) {
    if (TA == 0) {
      int mm = tid >> 2, kkb = (tid & 3) * 4;
      const float4 v = *(const float4*)(A + (size_t)(m0 + mm) * lda + k0 + kkb);
      As[kkb + 0][mm] = v.x; As[kkb + 1][mm] = v.y; As[kkb + 2][mm] = v.z; As[kkb + 3][mm] = v.w;
    } else {
      int kk = tid >> 4, mmb = (tid & 15) * 4;
      const float4 v = *(const float4*)(A + (size_t)(k0 + kk) * lda + m0 + mmb);
      As[kk][mmb + 0] = v.x; As[kk][mmb + 1] = v.y; As[kk][mmb + 2] = v.z; As[kk][mmb + 3] = v.w;
    }
    if (TB == 0) {
      int kk = tid >> 4, nnb = (tid & 15) * 4;
      const float4 v = *(const float4*)(B + (size_t)(k0 + kk) * ldb + n0 + nnb);
      Bs[kk][nnb + 0] = v.x; Bs[kk][nnb + 1] = v.y; Bs[kk][nnb + 2] = v.z; Bs[kk][nnb + 3] = v.w;
    } else {
      int nn = tid >> 2, kkb = (tid & 3) * 4;
      const float4 v = *(const float4*)(B + (size_t)(n0 + nn) * ldb + k0 + kkb);
      Bs[kkb + 0][nn] = v.x; Bs[kkb + 1][nn] = v.y; Bs[kkb + 2][nn] = v.z; Bs[kkb + 3][nn] = v.w;
    }
    __syncthreads();
    #pragma unroll
    for (int kk = 0; kk < 16; ++kk) {
      float a0 = As[kk][ty * 4 + 0], a1 = As[kk][ty * 4 + 1], a2 = As[kk][ty * 4 + 2], a3 = As[kk][ty * 4 + 3];
      float b0 = Bs[kk][tx * 4 + 0], b1 = Bs[kk][tx * 4 + 1], b2 = Bs[kk][tx * 4 + 2], b3 = Bs[kk][tx * 4 + 3];
      acc[0][0] += a0 * b0; acc[0][1] += a0 * b1; acc[0][2] += a0 * b2; acc[0][3] += a0 * b3;
      acc[1][0] += a1 * b0; acc[1][1] += a1 * b1; acc[1][2] += a1 * b2; acc[1][3] += a1 * b3;
      acc[2][0] += a2 * b0; acc[2][1] += a2 * b1; acc[2][2] += a2 * b2; acc[2][3] += a2 * b3;
      acc[3][0] += a3 * b0; acc[3][1] += a3 * b1; acc[3][2] += a3 * b2; acc[3][3] += a3 * b3;
    }
    __syncthreads();
  }
  #pragma unroll
  for (int r = 0; r < 4; ++r) {
    int m = m0 + ty * 4 + r;
    #pragma unroll
    for (int c = 0; c < 4; ++c) {
      int n = n0 + tx * 4 + c;
      float v = acc[r][c];
      if (MODE == 1) v = svec[m] + svec[n] + bptr[0] - 2.f * v;
      Cc[(size_t)m * ldc + n] = v;
    }
  }
}

// ---------------- loss ----------------
__global__ void loss_kernel(const float* __restrict__ logits, const float* __restrict__ gt,
                            double* __restrict__ acc)
{
  int base = blockIdx.x * 1024 + threadIdx.x;
  float local = 0.f;
  #pragma unroll
  for (int it = 0; it < 4; ++it) {
    int idx = base + it * 256;
    float l = logits[idx], g = gt[idx];
    float ls = (l > 0.f) ? -log1pf(expf(-l)) : (l - log1pf(expf(l)));   // log sigmoid(l)
    local += g * ls + (1.f - g) * (ls - l);
  }
  double dl = (double)local;
  for (int off = 32; off; off >>= 1) dl += __shfl_down(dl, off, 64);
  __shared__ double sred[4];
  if ((threadIdx.x & 63) == 0) sred[threadIdx.x >> 6] = dl;
  __syncthreads();
  if (threadIdx.x == 0) atomicAdd(acc, sred[0] + sred[1] + sred[2] + sred[3]);
}

__global__ void loss_fin(const double* __restrict__ acc, float* __restrict__ out)
{
  out[0] = (float)(-acc[0] / (double)((size_t)NN * NN));
}

// ---------------- eigh prep / post ----------------
__global__ void init_av(const float* __restrict__ logits, float* __restrict__ A0v,
                        float* __restrict__ V0v, float* __restrict__ G)
{
  int idx = blockIdx.x * 256 + threadIdx.x;   // NN*NN
  float g = 1.f / (1.f + expf(-logits[idx]));
  A0v[idx] = g;
  G[idx] = g;
  int i = idx >> 11, j = idx & (NN - 1);
  V0v[idx] = (i == j) ? 1.f : 0.f;
}

__global__ void get_diag(const float* __restrict__ A, float* __restrict__ d)
{
  int p = blockIdx.x * 256 + threadIdx.x;
  if (p < NN) d[p] = A[((size_t)p << 11) + p];
}

__global__ __launch_bounds__(256) void rank_kernel(const float* __restrict__ d, int* __restrict__ rnk)
{
  __shared__ float sd[NN];
  for (int i = threadIdx.x; i < NN; i += 256) sd[i] = d[i];
  __syncthreads();
  int p = blockIdx.x * 256 + threadIdx.x;
  float dp = sd[p];
  int r = 0;
  for (int q = 0; q < NN; ++q) {
    float dq = sd[q];
    r += (dq < dp) || (dq == dp && q < p);
  }
  rnk[p] = r;
}

__global__ __launch_bounds__(256) void colsum_kernel(const float* __restrict__ V, float* __restrict__ colsum)
{
  int b = blockIdx.x;                       // 256 blocks x 8 rows
  for (int c = threadIdx.x; c < NN; c += 256) {
    float acc = 0.f;
    #pragma unroll
    for (int r = 0; r < 8; ++r) acc += V[((size_t)(b * 8 + r) << 11) + c];
    atomicAdd(&colsum[c], acc);
  }
}

__global__ __launch_bounds__(256) void build_c(const float* __restrict__ V, const float* __restrict__ colsum,
        const float* __restrict__ d, const int* __restrict__ rnk, float* __restrict__ C)
{
  int idx = blockIdx.x * 256 + threadIdx.x; // NN*NN
  int i = idx >> 11, p = idx & (NN - 1);
  float sf = sqrtf(fmaxf(d[p], 1e-6f));
  float sgn = (colsum[p] >= 0.f) ? 1.f : -1.f;
  float v = V[idx] * sgn * sf;
  v = (v > 0.1f) ? v : 0.f;
  C[((size_t)i << 11) + rnk[p]] = v;
}

__global__ void rownorm(float* __restrict__ C)
{
  int i = blockIdx.x;
  float s = 0.f;
  for (int c = threadIdx.x; c < NN; c += 256) s += C[((size_t)i << 11) + c];
  for (int off = 32; off; off >>= 1) s += __shfl_down(s, off, 64);
  __shared__ float sw[4];
  if ((threadIdx.x & 63) == 0) sw[threadIdx.x >> 6] = s;
  __syncthreads();
  __shared__ float stot;
  if (threadIdx.x == 0) { float t = sw[0] + sw[1] + sw[2] + sw[3]; stot = (t == 0.f) ? 1.f : t; }
  __syncthreads();
  for (int c = threadIdx.x; c < NN; c += 256) C[((size_t)i << 11) + c] /= stot;
}

// ---------------- driver ----------------
extern "C" void kernel_launch(void* const* d_in, const int* in_sizes, int n_in,
                              void* d_out, int out_size, void* d_ws, size_t ws_size,
                              hipStream_t stream)
{
  const float* x     = (const float*)d_in[0];
  const float* eattr = (const float*)d_in[1];
  const float* gtrue = (const float*)d_in[2];
  const float* wself = (const float*)d_in[3];
  const float* wnbr  = (const float*)d_in[4];
  const float* bgnn  = (const float*)d_in[5];
  const float* wlin  = (const float*)d_in[6];
  const float* blin  = (const float*)d_in[7];
  const int*   eidx  = (const int*)d_in[8];

  float* out       = (float*)d_out;
  float* o_xnew    = out;                 // 2048*256
  float* o_acoarse = out + 524288;        // 2048*2048 (holds dense A until the final GEMM)
  float* o_c       = out + 4718592;       // 2048*2048
  float* o_loss    = out + 8912896;       // 1
  float* o_g       = out + 8912897;       // 2048*2048

  float*  ws       = (float*)d_ws;
  float*  w_h      = ws;                  // 524288
  float*  w_u      = ws + 524288;         // 524288
  float*  w_agg    = ws + 1048576;        // 262144
  float*  w_deg    = ws + 1310720;        // 2048
  float*  w_srow   = ws + 1312768;        // 2048
  float*  w_logits = ws + 1314816;        // 4194304 (reused as Tbuf after eigh)
  float*  w_a0     = ws + 5509120;        // 4194304  (A ping)
  float*  w_a1     = ws + 9703424;        // 4194304  (A pong)
  float*  w_v0     = ws + 13897728;       // 4194304  (V, in place)
  float*  w_ub0    = ws + 18092032;       // 65536
  float*  w_ub1    = ws + 18157568;       // 65536
  float*  w_d      = ws + 22286336;       // 2048
  int*    w_rank   = (int*)(ws + 22288384);  // 2048
  float*  w_colsum = ws + 22290432;       // 2048
  double* w_lacc   = (double*)(ws + 22292480); // 8-byte aligned

  hipMemsetAsync(w_agg, 0, (262144 + 2048) * sizeof(float), stream);
  hipMemsetAsync(w_colsum, 0, 2048 * sizeof(float) + sizeof(double), stream);
  hipMemsetAsync(o_acoarse, 0, (size_t)NN * NN * sizeof(float), stream);

  edge_deg_adj<<<NE / 256, 256, 0, stream>>>(eidx, eattr, w_deg, o_acoarse);
  edge_agg<<<(NE * 32) / 256, 256, 0, stream>>>(eidx, eattr, x, w_agg);
  div_agg<<<(NN * DE) / 256, 256, 0, stream>>>(w_agg, w_deg);
  gnn_h<<<dim3(DH / 16, NN / 16), 256, 0, stream>>>(x, w_agg, wself, wnbr, bgnn, w_h);
  u_s_kernel<<<NN, 256, 0, stream>>>(w_h, wlin, w_u, w_srow);

  gemm64<0, 1, 1><<<dim3(32, 32), 256, 0, stream>>>(NN, NN, DH, w_u, DH, w_h, DH,
                                                    w_logits, NN, w_srow, blin);
  loss_kernel<<<(NN * NN) / 1024, 256, 0, stream>>>(w_logits, gtrue, w_lacc);
  loss_fin<<<1, 1, 0, stream>>>(w_lacc, o_loss);

  init_av<<<(NN * NN) / 256, 256, 0, stream>>>(w_logits, w_a0, w_v0, o_g);

  // ------- block-Jacobi eigendecomposition: one fused dispatch per round -------
  const int R = (NBLK - 1) * OUTER_SWEEPS;
  const int LATE_START = (OUTER_SWEEPS - 2) * (NBLK - 1);   // last two sweeps get full polish
  // pre-solve of U_0 (direct read, rr_cur=-1); grid = solve blocks only
  jacobi_round<<<64, 64, 0, stream>>>(w_a0, w_a1, w_v0, w_ub0, -1, w_ub0, 0, LSW_EARLY);
  float* Ai = w_a0; float* Ao = w_a1; float* Uc = w_ub0; float* Un = w_ub1;
  for (int r = 0; r < R; ++r) {
    int rr = r % (NBLK - 1);
    int nrr = (r + 1 < R) ? ((r + 1) % (NBLK - 1)) : -1;
    int lsw = ((r + 1) >= LATE_START) ? LSW_LATE : LSW_EARLY;
    jacobi_round<<<64 + 4096 + 4096, 64, 0, stream>>>(Ai, Ao, w_v0, Uc, rr, Un, nrr, lsw);
    float* tp = Ai; Ai = Ao; Ao = tp;
    tp = Uc; Uc = Un; Un = tp;
  }
  // final A state is in Ai

  get_diag<<<NN / 256, 256, 0, stream>>>(Ai, w_d);
  rank_kernel<<<NN / 256, 256, 0, stream>>>(w_d, w_rank);
  colsum_kernel<<<NN / 8, 256, 0, stream>>>(w_v0, w_colsum);
  build_c<<<(NN * NN) / 256, 256, 0, stream>>>(w_v0, w_colsum, w_d, w_rank, o_c);
  rownorm<<<NN, 256, 0, stream>>>(o_c);

  gemm64<1, 0, 0><<<dim3(DH / 64, NN / 64), 256, 0, stream>>>(NN, DH, NN, o_c, NN, w_h, DH,
                                                              o_xnew, DH, nullptr, nullptr);
  float* Tbuf = w_logits;   // logits no longer needed
  gemm64<1, 0, 0><<<dim3(32, 32), 256, 0, stream>>>(NN, NN, NN, o_c, NN, o_acoarse, NN,
                                                    Tbuf, NN, nullptr, nullptr);
  gemm64<0, 0, 0><<<dim3(32, 32), 256, 0, stream>>>(NN, NN, NN, Tbuf, NN, o_c, NN,
                                                    o_acoarse, NN, nullptr, nullptr);
}

// Round 9
// 82391.235 us; speedup vs baseline: 1.2762x; 1.2762x over previous
//
#include <hip/hip_runtime.h>
#include <math.h>

#define NN    2048
#define DE    128
#define DH    256
#define NE    65536
#define NBLK  128      // outer blocks of 16 rows
#define BS    16
#define OUTER_SWEEPS 8
#define LSW_EARLY 2    // local sweeps, early outer sweeps (rate only, not accuracy)
#define LSW_LATE  6    // local sweeps, last two outer sweeps (polish)

// rotation params — identical formula to all passing versions
__device__ __forceinline__ void jrot2(float app, float aqq, float apq, float& c, float& s) {
  if (fabsf(apq) <= 1e-30f) { c = 1.f; s = 0.f; return; }
  float tau = (aqq - app) / (2.f * apq);
  float den = fabsf(tau) + sqrtf(1.f + tau * tau);
  float t = ((tau >= 0.f) ? 1.f : -1.f) / den;
  c = 1.f / sqrtf(1.f + t * t);
  s = t * c;
}

// round-robin (circle method) pairing of 128 blocks; round rr in [0,127)
__device__ __forceinline__ void pair_of(int rr, int i, int& bp, int& bq) {
  int p, q;
  if (i == 0) { p = NBLK - 1; q = rr % (NBLK - 1); }
  else { p = (rr + i) % (NBLK - 1); q = (rr - i + (NBLK - 1)) % (NBLK - 1); }
  bp = min(p, q); bq = max(p, q);
}

// inverse: which pair index holds 16-block g in round rr
__device__ __forceinline__ int inv_pair(int rr, int g) {
  if (g == NBLK - 1) return 0;
  if (g == rr % (NBLK - 1)) return 0;
  int d = (g - rr) % (NBLK - 1); if (d < 0) d += (NBLK - 1);
  return (d <= NBLK / 2 - 1) ? d : (NBLK - 1 - d);
}

// ---------------- fused per-round kernel ----------------
// blocks [0,64):        solve U_{r+1} from Ain (state r-1) with on-the-fly U_r update
// blocks [64,4160):     A-apply i<=j: Aout(i,j) = Ui^T Ain(i,j) Uj, mirror to (j,i)
// blocks [4160,8256):   V-apply: V(:,Sj) = V(:,Sj) Uj   (in place)
__global__ __launch_bounds__(64) void jacobi_round(
    const float* __restrict__ Ain, float* __restrict__ Aout,
    float* __restrict__ V,
    const float* __restrict__ Ucur, int rr_cur,
    float* __restrict__ Unext, int rr_next, int lsw)
{
  __shared__ float L0[32][36];   // AA / SA / Tvt / S-pong
  __shared__ float L1[32][36];   // U1t
  __shared__ float L2[32][36];   // U2t / U2n / U2v
  __shared__ float L3[32][36];   // Tt
  __shared__ float L4[32][36];   // S-ping
  __shared__ float L5[32][36];   // Ut
  __shared__ float rc[16], rs[16];
  __shared__ int pa[16], pb[16];
  const int tid = threadIdx.x;
  const int b = blockIdx.x;

  if (b < 64) {
    // ================= SOLVE =================
    if (rr_next < 0) return;
    int pP, pQ; pair_of(rr_next, b, pP, pQ);   // pP < pQ
    {   // Ut = I
      int a = tid >> 1, ch = (tid & 1) * 16;
      #pragma unroll
      for (int q = 0; q < 4; ++q) {
        int c4 = ch + q * 4;
        L5[a][c4]     = (a == c4)     ? 1.f : 0.f;
        L5[a][c4 + 1] = (a == c4 + 1) ? 1.f : 0.f;
        L5[a][c4 + 2] = (a == c4 + 2) ? 1.f : 0.f;
        L5[a][c4 + 3] = (a == c4 + 3) ? 1.f : 0.f;
      }
    }
    if (rr_cur < 0) {
      // direct load of the 32x32 [pP pP; pP pQ; ...] from Ain
      int a = tid >> 1, ch = (tid & 1) * 16;
      int gr = (a < BS) ? (pP * BS + a) : (pQ * BS + a - BS);
      #pragma unroll
      for (int q = 0; q < 4; ++q) {
        int c4 = ch + q * 4;
        int gc = (c4 < BS) ? (pP * BS + c4) : (pQ * BS + c4 - BS);
        *(float4*)&L4[a][c4] = *(const float4*)(Ain + ((size_t)gr << 11) + gc);
      }
      __syncthreads();
    } else {
      const int i1 = inv_pair(rr_cur, pP), i2 = inv_pair(rr_cur, pQ);
      int bp1, bq1; pair_of(rr_cur, i1, bp1, bq1);
      int bp2, bq2; pair_of(rr_cur, i2, bp2, bq2);
      const int o1 = (pP == bp1) ? 0 : 16;
      const int o2 = (pQ == bp2) ? 0 : 16;
      {   // load U1t, U2t (transposed storage as written by previous solve)
        int a = tid >> 1, ch = (tid & 1) * 16;
        #pragma unroll
        for (int q = 0; q < 4; ++q) {
          int c4 = ch + q * 4;
          *(float4*)&L1[a][c4] = *(const float4*)(Ucur + ((size_t)i1 << 10) + (a << 5) + c4);
          *(float4*)&L2[a][c4] = *(const float4*)(Ucur + ((size_t)i2 << 10) + (a << 5) + c4);
        }
      }
      // three supertiles: (i1,i1)->S[0:16,0:16]; (i1,i2)->S[0:16,16:32]+mirror; (i2,i2)->S[16:,16:]
      #pragma unroll
      for (int t3 = 0; t3 < 3; ++t3) {
        const int bpa = (t3 == 2) ? bp2 : bp1, bqa = (t3 == 2) ? bq2 : bq1;
        const int bpb = (t3 == 0) ? bp1 : bp2, bqb = (t3 == 0) ? bq1 : bq2;
        const float (*Ua)[36] = (t3 == 2) ? L2 : L1;
        const float (*Ub)[36] = (t3 == 0) ? L1 : L2;
        const int oa = (t3 == 2) ? o2 : o1;
        const int ob = (t3 == 0) ? o1 : o2;
        const int dr = (t3 == 2) ? 16 : 0;
        const int dc = (t3 == 0) ? 0 : 16;
        {   // load supertile
          int a = tid >> 1, ch = (tid & 1) * 16;
          int gr = (a < BS) ? (bpa * BS + a) : (bqa * BS + a - BS);
          #pragma unroll
          for (int q = 0; q < 4; ++q) {
            int c4 = ch + q * 4;
            int gc = (c4 < BS) ? (bpb * BS + c4) : (bqb * BS + c4 - BS);
            *(float4*)&L0[a][c4] = *(const float4*)(Ain + ((size_t)gr << 11) + gc);
          }
        }
        __syncthreads();
        {   // T1(16x32) = Ua(:,oa:oa+16)^T * AA
          int rT = tid >> 2, cb = (tid & 3) * 8;
          float t1[8] = {};
          for (int k = 0; k < 32; ++k) {
            float u = Ua[oa + rT][k];
            #pragma unroll
            for (int c = 0; c < 8; ++c) t1[c] += u * L0[k][cb + c];
          }
          #pragma unroll
          for (int c = 0; c < 8; ++c) L3[rT][cb + c] = t1[c];
        }
        __syncthreads();
        {   // Q(16x16) = T1 * Ub(:,ob:ob+16)
          int rQ = tid >> 2, c0 = (tid & 3) * 4;
          float qv[4] = {};
          for (int k = 0; k < 32; ++k) {
            float tv = L3[rQ][k];
            #pragma unroll
            for (int c = 0; c < 4; ++c) qv[c] += tv * Ub[ob + c0 + c][k];
          }
          #pragma unroll
          for (int c = 0; c < 4; ++c) {
            L4[dr + rQ][dc + c0 + c] = qv[c];
            if (t3 == 1) L4[dc + c0 + c][dr + rQ] = qv[c];   // symmetric mirror
          }
        }
        __syncthreads();
      }
    }
    // -------- local Jacobi on S (ping-pong L4/L0), accumulate Ut (L5) --------
    float (*Sc)[36] = L4;     // current
    float (*Sn)[36] = L0;     // next (L0 is free after reconstruction)
    for (int sw = 0; sw < lsw; ++sw) {
      {   // convergence check (wave-uniform)
        float off2 = 0.f, d2 = 0.f;
        int a = tid >> 1, ch = (tid & 1) * 16;
        for (int c = ch; c < ch + 16; ++c) {
          float v = Sc[a][c];
          if (c == a) d2 += v * v; else off2 += v * v;
        }
        #pragma unroll
        for (int o = 1; o < 64; o <<= 1) {
          off2 += __shfl_xor(off2, o, 64);
          d2   += __shfl_xor(d2, o, 64);
        }
        if (off2 <= 1e-11f * d2) break;
      }
      for (int r2 = 0; r2 < 31; ++r2) {
        if (tid < 16) {
          int aa, bb;
          if (tid == 0) { aa = 31; bb = r2; }
          else { aa = (r2 + tid) % 31; bb = (r2 - tid + 31) % 31; }
          int pp = min(aa, bb), qq = max(aa, bb);
          pa[tid] = pp; pb[tid] = qq;
          float c, s; jrot2(Sc[pp][pp], Sc[qq][qq], Sc[pp][qq], c, s);
          rc[tid] = c; rs[tid] = s;
        }
        __syncthreads();
        // fused two-sided update Sn = J^T Sc J — disjoint pairs, one LDS phase.
        // Algebraically identical to row-phase-then-col-phase (different rounding assoc.)
        #pragma unroll
        for (int it = 0; it < 4; ++it) {
          int t = tid + it * 64;
          int k = t >> 4, m = t & 15;
          float ck = rc[k], sk = rs[k]; int P = pa[k], Q = pb[k];
          float cm = rc[m], sm = rs[m]; int Cp = pa[m], Cq = pb[m];
          float a0 = Sc[P][Cp], b0 = Sc[P][Cq];
          float c0 = Sc[Q][Cp], d0 = Sc[Q][Cq];
          float r0p = ck * a0 - sk * c0;   // row-rotated, col Cp
          float r0q = ck * b0 - sk * d0;   // row-rotated, col Cq
          float r1p = sk * a0 + ck * c0;
          float r1q = sk * b0 + ck * d0;
          Sn[P][Cp] = cm * r0p - sm * r0q;
          Sn[P][Cq] = sm * r0p + cm * r0q;
          Sn[Q][Cp] = cm * r1p - sm * r1q;
          Sn[Q][Cq] = sm * r1p + cm * r1q;
        }
        #pragma unroll
        for (int it = 0; it < 2; ++it) {   // Ut row phase (b128, in place, disjoint rows)
          int t = tid + it * 64;
          int k = t >> 3, q4 = (t & 7) << 2;
          float c = rc[k], s = rs[k]; int P = pa[k], Q = pb[k];
          float4 xp = *(const float4*)&L5[P][q4];
          float4 xq = *(const float4*)&L5[Q][q4];
          *(float4*)&L5[P][q4] = make_float4(c*xp.x - s*xq.x, c*xp.y - s*xq.y,
                                             c*xp.z - s*xq.z, c*xp.w - s*xq.w);
          *(float4*)&L5[Q][q4] = make_float4(s*xp.x + c*xq.x, s*xp.y + c*xq.y,
                                             s*xp.z + c*xq.z, s*xp.w + c*xq.w);
        }
        __syncthreads();
        float (*tp)[36] = Sc; Sc = Sn; Sn = tp;   // swap ping-pong
      }
    }
    {   // write Ut (transposed layout: Unext[b][r*32+k] = U[k][r])
      int r = tid >> 1, ch = (tid & 1) * 16;
      #pragma unroll
      for (int q = 0; q < 4; ++q) {
        int c4 = ch + q * 4;
        *(float4*)(Unext + ((size_t)b << 10) + (r << 5) + c4) = *(const float4*)&L5[r][c4];
      }
    }
  } else if (b < 64 + 4096) {
    // ================= A-APPLY (i<=j, ping-pong, mirror) =================
    const int idx = b - 64;
    const int i = idx >> 6, j = idx & 63;
    if (i > j) return;
    const int ta = tid >> 3, tb = tid & 7;
    int bpi, bqi; pair_of(rr_cur, i, bpi, bqi);
    int bpj, bqj; pair_of(rr_cur, j, bpj, bqj);
    {
      int a = tid >> 1, ch = (tid & 1) * 16;
      int gr = (a < BS) ? (bpi * BS + a) : (bqi * BS + a - BS);
      #pragma unroll
      for (int q = 0; q < 4; ++q) {
        int c4 = ch + q * 4;
        *(float4*)&L1[a][c4] = *(const float4*)(Ucur + ((size_t)i << 10) + (a << 5) + c4);
        const float4 u = *(const float4*)(Ucur + ((size_t)j << 10) + (a << 5) + c4);
        L2[c4][a] = u.x; L2[c4 + 1][a] = u.y; L2[c4 + 2][a] = u.z; L2[c4 + 3][a] = u.w;
        int gc = (c4 < BS) ? (bpj * BS + c4) : (bqj * BS + c4 - BS);
        *(float4*)&L0[a][c4] = *(const float4*)(Ain + ((size_t)gr << 11) + gc);
      }
    }
    __syncthreads();
    {   // stage 1: T = U1^T * SA, stored transposed into L3
      float acc[4][4] = {};
      for (int k4 = 0; k4 < 8; ++k4) {
        const float4 sa0 = *(const float4*)&L0[4 * k4 + 0][tb << 2];
        const float4 sa1 = *(const float4*)&L0[4 * k4 + 1][tb << 2];
        const float4 sa2 = *(const float4*)&L0[4 * k4 + 2][tb << 2];
        const float4 sa3 = *(const float4*)&L0[4 * k4 + 3][tb << 2];
        #pragma unroll
        for (int r = 0; r < 4; ++r) {
          const float4 u = *(const float4*)&L1[(ta << 2) + r][k4 << 2];
          acc[r][0] += u.x*sa0.x; acc[r][1] += u.x*sa0.y; acc[r][2] += u.x*sa0.z; acc[r][3] += u.x*sa0.w;
          acc[r][0] += u.y*sa1.x; acc[r][1] += u.y*sa1.y; acc[r][2] += u.y*sa1.z; acc[r][3] += u.y*sa1.w;
          acc[r][0] += u.z*sa2.x; acc[r][1] += u.z*sa2.y; acc[r][2] += u.z*sa2.z; acc[r][3] += u.z*sa2.w;
          acc[r][0] += u.w*sa3.x; acc[r][1] += u.w*sa3.y; acc[r][2] += u.w*sa3.z; acc[r][3] += u.w*sa3.w;
        }
      }
      #pragma unroll
      for (int r = 0; r < 4; ++r)
        #pragma unroll
        for (int c = 0; c < 4; ++c)
          L3[(tb << 2) + c][(ta << 2) + r] = acc[r][c];
    }
    __syncthreads();
    float o[4][4] = {};
    for (int k = 0; k < 32; ++k) {   // stage 2: Out = T * U2
      const float4 tv = *(const float4*)&L3[k][ta << 2];
      const float4 u  = *(const float4*)&L2[k][tb << 2];
      o[0][0]+=tv.x*u.x; o[0][1]+=tv.x*u.y; o[0][2]+=tv.x*u.z; o[0][3]+=tv.x*u.w;
      o[1][0]+=tv.y*u.x; o[1][1]+=tv.y*u.y; o[1][2]+=tv.y*u.z; o[1][3]+=tv.y*u.w;
      o[2][0]+=tv.z*u.x; o[2][1]+=tv.z*u.y; o[2][2]+=tv.z*u.z; o[2][3]+=tv.z*u.w;
      o[3][0]+=tv.w*u.x; o[3][1]+=tv.w*u.y; o[3][2]+=tv.w*u.z; o[3][3]+=tv.w*u.w;
    }
    #pragma unroll
    for (int r = 0; r < 4; ++r) {
      int a = (ta << 2) + r;
      int gr = (a < BS) ? (bpi * BS + a) : (bqi * BS + a - BS);
      int c4 = tb << 2;
      int gc = (c4 < BS) ? (bpj * BS + c4) : (bqj * BS + c4 - BS);
      *(float4*)(Aout + ((size_t)gr << 11) + gc) = make_float4(o[r][0], o[r][1], o[r][2], o[r][3]);
    }
    if (i != j) {   // mirror via LDS
      __syncthreads();
      #pragma unroll
      for (int r = 0; r < 4; ++r)
        #pragma unroll
        for (int c = 0; c < 4; ++c)
          L3[(tb << 2) + c][(ta << 2) + r] = o[r][c];
      __syncthreads();
      int a = tid >> 1, ch = (tid & 1) * 16;
      int gr2 = (a < BS) ? (bpj * BS + a) : (bqj * BS + a - BS);
      #pragma unroll
      for (int q = 0; q < 4; ++q) {
        int c4 = ch + q * 4;
        int gc2 = (c4 < BS) ? (bpi * BS + c4) : (bqi * BS + c4 - BS);
        *(float4*)(Aout + ((size_t)gr2 << 11) + gc2) = *(const float4*)&L3[a][c4];
      }
    }
  } else {
    // ================= V-APPLY (in place) =================
    const int vb = b - (64 + 4096);
    const int j = vb >> 6, rt = vb & 63;
    int bpj, bqj; pair_of(rr_cur, j, bpj, bqj);
    const int ta = tid >> 3, tb = tid & 7;
    {
      int a = tid >> 1, ch = (tid & 1) * 16;
      #pragma unroll
      for (int q = 0; q < 4; ++q) {
        int c4 = ch + q * 4;
        const float4 u = *(const float4*)(Ucur + ((size_t)j << 10) + (a << 5) + c4);
        L2[c4][a] = u.x; L2[c4 + 1][a] = u.y; L2[c4 + 2][a] = u.z; L2[c4 + 3][a] = u.w;
        int gc = (c4 < BS) ? (bpj * BS + c4) : (bqj * BS + c4 - BS);
        const float4 vv = *(const float4*)(V + ((size_t)(rt * 32 + a) << 11) + gc);
        L0[c4][a] = vv.x; L0[c4 + 1][a] = vv.y; L0[c4 + 2][a] = vv.z; L0[c4 + 3][a] = vv.w;
      }
    }
    __syncthreads();
    float o[4][4] = {};
    for (int k = 0; k < 32; ++k) {
      const float4 tv = *(const float4*)&L0[k][ta << 2];
      const float4 u  = *(const float4*)&L2[k][tb << 2];
      o[0][0]+=tv.x*u.x; o[0][1]+=tv.x*u.y; o[0][2]+=tv.x*u.z; o[0][3]+=tv.x*u.w;
      o[1][0]+=tv.y*u.x; o[1][1]+=tv.y*u.y; o[1][2]+=tv.y*u.z; o[1][3]+=tv.y*u.w;
      o[2][0]+=tv.z*u.x; o[2][1]+=tv.z*u.y; o[2][2]+=tv.z*u.z; o[2][3]+=tv.z*u.w;
      o[3][0]+=tv.w*u.x; o[3][1]+=tv.w*u.y; o[3][2]+=tv.w*u.z; o[3][3]+=tv.w*u.w;
    }
    #pragma unroll
    for (int r = 0; r < 4; ++r) {
      int c4 = tb << 2;
      int gc = (c4 < BS) ? (bpj * BS + c4) : (bqj * BS + c4 - BS);
      *(float4*)(V + ((size_t)(rt * 32 + (ta << 2) + r) << 11) + gc) =
          make_float4(o[r][0], o[r][1], o[r][2], o[r][3]);
    }
  }
}

// ---------------- graph / SAGE stage ----------------
__global__ void edge_deg_adj(const int* __restrict__ ei, const float* __restrict__ attr,
                             float* __restrict__ deg, float* __restrict__ Adense)
{
  int e = blockIdx.x * 256 + threadIdx.x;
  if (e >= NE) return;
  int s = ei[e], t = ei[NE + e];
  atomicAdd(&deg[t], 1.0f);
  Adense[((size_t)s << 11) + t] = attr[e];
}

__global__ void edge_agg(const int* __restrict__ ei, const float* __restrict__ attr,
                         const float* __restrict__ x, float* __restrict__ agg)
{
  int t0 = blockIdx.x * 256 + threadIdx.x;   // NE*32 items
  int e = t0 >> 5, c4 = (t0 & 31) * 4;
  int s = ei[e], t = ei[NE + e];
  float a = attr[e];
  const float4 xv = *(const float4*)(x + (size_t)s * DE + c4);
  atomicAdd(&agg[(size_t)t * DE + c4 + 0], xv.x * a);
  atomicAdd(&agg[(size_t)t * DE + c4 + 1], xv.y * a);
  atomicAdd(&agg[(size_t)t * DE + c4 + 2], xv.z * a);
  atomicAdd(&agg[(size_t)t * DE + c4 + 3], xv.w * a);
}

__global__ void div_agg(float* __restrict__ agg, const float* __restrict__ deg)
{
  int idx = blockIdx.x * 256 + threadIdx.x;  // NN*DE
  agg[idx] /= fmaxf(deg[idx >> 7], 1.0f);
}

__global__ __launch_bounds__(256) void gnn_h(const float* __restrict__ x, const float* __restrict__ agg,
        const float* __restrict__ wself, const float* __restrict__ wnbr,
        const float* __restrict__ bg, float* __restrict__ h)
{
  __shared__ float xs[16][DE];
  __shared__ float as[16][DE];
  int tx = threadIdx.x % 16, ty = threadIdx.x / 16;
  int i0 = blockIdx.y * 16, j = blockIdx.x * 16 + tx;
  for (int e = threadIdx.x; e < 16 * DE; e += 256) {
    int r = e >> 7, k = e & 127;
    xs[r][k] = x[(size_t)(i0 + r) * DE + k];
    as[r][k] = agg[(size_t)(i0 + r) * DE + k];
  }
  __syncthreads();
  float acc = bg[j];
  for (int k = 0; k < DE; ++k)
    acc += xs[ty][k] * wself[k * DH + j] + as[ty][k] * wnbr[k * DH + j];
  h[(size_t)(i0 + ty) * DH + j] = fmaxf(acc, 0.f);
}

__global__ void u_s_kernel(const float* __restrict__ h, const float* __restrict__ wlin,
                           float* __restrict__ u, float* __restrict__ srow)
{
  int i = blockIdx.x, j = threadIdx.x;      // 2048 blocks x 256
  float hv = h[(size_t)i * DH + j];
  float w = wlin[j];
  u[(size_t)i * DH + j] = hv * w;
  float p = hv * hv * w;
  for (int off = 32; off; off >>= 1) p += __shfl_down(p, off, 64);
  __shared__ float sw[4];
  if ((j & 63) == 0) sw[j >> 6] = p;
  __syncthreads();
  if (j == 0) srow[i] = sw[0] + sw[1] + sw[2] + sw[3];
}

// ---------------- generic 64x64x16 tiled fp32 GEMM ----------------
template<int TA, int TB, int MODE>
__global__ __launch_bounds__(256) void gemm64(int M, int Nn, int K,
            const float* __restrict__ A, int lda,
            const float* __restrict__ B, int ldb,
            float* __restrict__ Cc, int ldc,
            const float* __restrict__ svec, const float* __restrict__ bptr)
{
  __shared__ float As[16][65];
  __shared__ float Bs[16][65];
  const int tid = threadIdx.x;
  const int tx = tid % 16, ty = tid / 16;
  const int m0 = blockIdx.y * 64, n0 = blockIdx.x * 64;
  float acc[4][4] = {};
  for (int k0 = 0; k0 < K; k0 += 16) {
    if (TA == 0) {
      int mm = tid >> 2, kkb = (tid & 3) * 4;
      const float4 v = *(const float4*)(A + (size_t)(m0 + mm) * lda + k0 + kkb);
      As[kkb + 0][mm] = v.x; As[kkb + 1][mm] = v.y; As[kkb + 2][mm] = v.z; As[kkb + 3][mm] = v.w;
    } else {
      int kk = tid >> 4, mmb = (tid & 15) * 4;
      const float4 v = *(const float4*)(A + (size_t)(k0 + kk) * lda + m0 + mmb);
      As[kk][mmb + 0] = v.x; As[kk][mmb + 1] = v.y; As[kk][mmb + 2] = v.z; As[kk][mmb + 3] = v.w;
    }
    if (TB == 0) {
      int kk = tid >> 4, nnb = (tid & 15) * 4;
      const float4 v = *(const float4*)(B + (size_t)(k0 + kk) * ldb + n0 + nnb);
      Bs[kk][nnb + 0] = v.x; Bs[kk][nnb + 1] = v.y; Bs[kk][nnb + 2] = v.z; Bs[kk][nnb + 3] = v.w;
    } else {
      int nn = tid >> 2, kkb = (tid & 3) * 4;
      const float4 v = *(const float4*)(B + (size_t)(n0 + nn) * ldb + k0 + kkb);
      Bs[kkb + 0][nn] = v.x; Bs[kkb + 1][nn] = v.y; Bs[kkb + 2][nn] = v.z; Bs[kkb + 3][nn] = v.w;
    }
    __syncthreads();
    #pragma unroll
    for (int kk = 0; kk < 16; ++kk) {
      float a0 = As[kk][ty * 4 + 0], a1 = As[kk][ty * 4 + 1], a2 = As[kk][ty * 4 + 2], a3 = As[kk][ty * 4 + 3];
      float b0 = Bs[kk][tx * 4 + 0], b1 = Bs[kk][tx * 4 + 1], b2 = Bs[kk][tx * 4 + 2], b3 = Bs[kk][tx * 4 + 3];
      acc[0][0] += a0 * b0; acc[0][1] += a0 * b1; acc[0][2] += a0 * b2; acc[0][3] += a0 * b3;
      acc[1][0] += a1 * b0; acc[1][1] += a1 * b1; acc[1][2] += a1 * b2; acc[1][3] += a1 * b3;
      acc[2][0] += a2 * b0; acc[2][1] += a2 * b1; acc[2][2] += a2 * b2; acc[2][3] += a2 * b3;
      acc[3][0] += a3 * b0; acc[3][1] += a3 * b1; acc[3][2] += a3 * b2; acc[3][3] += a3 * b3;
    }
    __syncthreads();
  }
  #pragma unroll
  for (int r = 0; r < 4; ++r) {
    int m = m0 + ty * 4 + r;
    #pragma unroll
    for (int c = 0; c < 4; ++c) {
      int n = n0 + tx * 4 + c;
      float v = acc[r][c];
      if (MODE == 1) v = svec[m] + svec[n] + bptr[0] - 2.f * v;
      Cc[(size_t)m * ldc + n] = v;
    }
  }
}

// ---------------- loss ----------------
__global__ void loss_kernel(const float* __restrict__ logits, const float* __restrict__ gt,
                            double* __restrict__ acc)
{
  int base = blockIdx.x * 1024 + threadIdx.x;
  float local = 0.f;
  #pragma unroll
  for (int it = 0; it < 4; ++it) {
    int idx = base + it * 256;
    float l = logits[idx], g = gt[idx];
    float ls = (l > 0.f) ? -log1pf(expf(-l)) : (l - log1pf(expf(l)));   // log sigmoid(l)
    local += g * ls + (1.f - g) * (ls - l);
  }
  double dl = (double)local;
  for (int off = 32; off; off >>= 1) dl += __shfl_down(dl, off, 64);
  __shared__ double sred[4];
  if ((threadIdx.x & 63) == 0) sred[threadIdx.x >> 6] = dl;
  __syncthreads();
  if (threadIdx.x == 0) atomicAdd(acc, sred[0] + sred[1] + sred[2] + sred[3]);
}

__global__ void loss_fin(const double* __restrict__ acc, float* __restrict__ out)
{
  out[0] = (float)(-acc[0] / (double)((size_t)NN * NN));
}

// ---------------- eigh prep / post ----------------
__global__ void init_av(const float* __restrict__ logits, float* __restrict__ A0v,
                        float* __restrict__ V0v, float* __restrict__ G)
{
  int idx = blockIdx.x * 256 + threadIdx.x;   // NN*NN
  float g = 1.f / (1.f + expf(-logits[idx]));
  A0v[idx] = g;
  G[idx] = g;
  int i = idx >> 11, j = idx & (NN - 1);
  V0v[idx] = (i == j) ? 1.f : 0.f;
}

__global__ void get_diag(const float* __restrict__ A, float* __restrict__ d)
{
  int p = blockIdx.x * 256 + threadIdx.x;
  if (p < NN) d[p] = A[((size_t)p << 11) + p];
}

__global__ __launch_bounds__(256) void rank_kernel(const float* __restrict__ d, int* __restrict__ rnk)
{
  __shared__ float sd[NN];
  for (int i = threadIdx.x; i < NN; i += 256) sd[i] = d[i];
  __syncthreads();
  int p = blockIdx.x * 256 + threadIdx.x;
  float dp = sd[p];
  int r = 0;
  for (int q = 0; q < NN; ++q) {
    float dq = sd[q];
    r += (dq < dp) || (dq == dp && q < p);
  }
  rnk[p] = r;
}

__global__ __launch_bounds__(256) void colsum_kernel(const float* __restrict__ V, float* __restrict__ colsum)
{
  int b = blockIdx.x;                       // 256 blocks x 8 rows
  for (int c = threadIdx.x; c < NN; c += 256) {
    float acc = 0.f;
    #pragma unroll
    for (int r = 0; r < 8; ++r) acc += V[((size_t)(b * 8 + r) << 11) + c];
    atomicAdd(&colsum[c], acc);
  }
}

__global__ __launch_bounds__(256) void build_c(const float* __restrict__ V, const float* __restrict__ colsum,
        const float* __restrict__ d, const int* __restrict__ rnk, float* __restrict__ C)
{
  int idx = blockIdx.x * 256 + threadIdx.x; // NN*NN
  int i = idx >> 11, p = idx & (NN - 1);
  float sf = sqrtf(fmaxf(d[p], 1e-6f));
  float sgn = (colsum[p] >= 0.f) ? 1.f : -1.f;
  float v = V[idx] * sgn * sf;
  v = (v > 0.1f) ? v : 0.f;
  C[((size_t)i << 11) + rnk[p]] = v;
}

__global__ void rownorm(float* __restrict__ C)
{
  int i = blockIdx.x;
  float s = 0.f;
  for (int c = threadIdx.x; c < NN; c += 256) s += C[((size_t)i << 11) + c];
  for (int off = 32; off; off >>= 1) s += __shfl_down(s, off, 64);
  __shared__ float sw[4];
  if ((threadIdx.x & 63) == 0) sw[threadIdx.x >> 6] = s;
  __syncthreads();
  __shared__ float stot;
  if (threadIdx.x == 0) { float t = sw[0] + sw[1] + sw[2] + sw[3]; stot = (t == 0.f) ? 1.f : t; }
  __syncthreads();
  for (int c = threadIdx.x; c < NN; c += 256) C[((size_t)i << 11) + c] /= stot;
}

// ---------------- driver ----------------
extern "C" void kernel_launch(void* const* d_in, const int* in_sizes, int n_in,
                              void* d_out, int out_size, void* d_ws, size_t ws_size,
                              hipStream_t stream)
{
  const float* x     = (const float*)d_in[0];
  const float* eattr = (const float*)d_in[1];
  const float* gtrue = (const float*)d_in[2];
  const float* wself = (const float*)d_in[3];
  const float* wnbr  = (const float*)d_in[4];
  const float* bgnn  = (const float*)d_in[5];
  const float* wlin  = (const float*)d_in[6];
  const float* blin  = (const float*)d_in[7];
  const int*   eidx  = (const int*)d_in[8];

  float* out       = (float*)d_out;
  float* o_xnew    = out;                 // 2048*256
  float* o_acoarse = out + 524288;        // 2048*2048 (holds dense A until the final GEMM)
  float* o_c       = out + 4718592;       // 2048*2048
  float* o_loss    = out + 8912896;       // 1
  float* o_g       = out + 8912897;       // 2048*2048

  float*  ws       = (float*)d_ws;
  float*  w_h      = ws;                  // 524288
  float*  w_u      = ws + 524288;         // 524288
  float*  w_agg    = ws + 1048576;        // 262144
  float*  w_deg    = ws + 1310720;        // 2048
  float*  w_srow   = ws + 1312768;        // 2048
  float*  w_logits = ws + 1314816;        // 4194304 (reused as Tbuf after eigh)
  float*  w_a0     = ws + 5509120;        // 4194304  (A ping)
  float*  w_a1     = ws + 9703424;        // 4194304  (A pong)
  float*  w_v0     = ws + 13897728;       // 4194304  (V, in place)
  float*  w_ub0    = ws + 18092032;       // 65536
  float*  w_ub1    = ws + 18157568;       // 65536
  float*  w_d      = ws + 22286336;       // 2048
  int*    w_rank   = (int*)(ws + 22288384);  // 2048
  float*  w_colsum = ws + 22290432;       // 2048
  double* w_lacc   = (double*)(ws + 22292480); // 8-byte aligned

  hipMemsetAsync(w_agg, 0, (262144 + 2048) * sizeof(float), stream);
  hipMemsetAsync(w_colsum, 0, 2048 * sizeof(float) + sizeof(double), stream);
  hipMemsetAsync(o_acoarse, 0, (size_t)NN * NN * sizeof(float), stream);

  edge_deg_adj<<<NE / 256, 256, 0, stream>>>(eidx, eattr, w_deg, o_acoarse);
  edge_agg<<<(NE * 32) / 256, 256, 0, stream>>>(eidx, eattr, x, w_agg);
  div_agg<<<(NN * DE) / 256, 256, 0, stream>>>(w_agg, w_deg);
  gnn_h<<<dim3(DH / 16, NN / 16), 256, 0, stream>>>(x, w_agg, wself, wnbr, bgnn, w_h);
  u_s_kernel<<<NN, 256, 0, stream>>>(w_h, wlin, w_u, w_srow);

  gemm64<0, 1, 1><<<dim3(32, 32), 256, 0, stream>>>(NN, NN, DH, w_u, DH, w_h, DH,
                                                    w_logits, NN, w_srow, blin);
  loss_kernel<<<(NN * NN) / 1024, 256, 0, stream>>>(w_logits, gtrue, w_lacc);
  loss_fin<<<1, 1, 0, stream>>>(w_lacc, o_loss);

  init_av<<<(NN * NN) / 256, 256, 0, stream>>>(w_logits, w_a0, w_v0, o_g);

  // ------- block-Jacobi eigendecomposition: one fused dispatch per round -------
  const int R = (NBLK - 1) * OUTER_SWEEPS;
  const int LATE_START = (OUTER_SWEEPS - 2) * (NBLK - 1);   // last two sweeps get full polish
  // pre-solve of U_0 (direct read, rr_cur=-1); grid = solve blocks only
  jacobi_round<<<64, 64, 0, stream>>>(w_a0, w_a1, w_v0, w_ub0, -1, w_ub0, 0, LSW_EARLY);
  float* Ai = w_a0; float* Ao = w_a1; float* Uc = w_ub0; float* Un = w_ub1;
  for (int r = 0; r < R; ++r) {
    int rr = r % (NBLK - 1);
    int nrr = (r + 1 < R) ? ((r + 1) % (NBLK - 1)) : -1;
    int lsw = ((r + 1) >= LATE_START) ? LSW_LATE : LSW_EARLY;
    jacobi_round<<<64 + 4096 + 4096, 64, 0, stream>>>(Ai, Ao, w_v0, Uc, rr, Un, nrr, lsw);
    float* tp = Ai; Ai = Ao; Ao = tp;
    tp = Uc; Uc = Un; Un = tp;
  }
  // final A state is in Ai

  get_diag<<<NN / 256, 256, 0, stream>>>(Ai, w_d);
  rank_kernel<<<NN / 256, 256, 0, stream>>>(w_d, w_rank);
  colsum_kernel<<<NN / 8, 256, 0, stream>>>(w_v0, w_colsum);
  build_c<<<(NN * NN) / 256, 256, 0, stream>>>(w_v0, w_colsum, w_d, w_rank, o_c);
  rownorm<<<NN, 256, 0, stream>>>(o_c);

  gemm64<1, 0, 0><<<dim3(DH / 64, NN / 64), 256, 0, stream>>>(NN, DH, NN, o_c, NN, w_h, DH,
                                                              o_xnew, DH, nullptr, nullptr);
  float* Tbuf = w_logits;   // logits no longer needed
  gemm64<1, 0, 0><<<dim3(32, 32), 256, 0, stream>>>(NN, NN, NN, o_c, NN, o_acoarse, NN,
                                                    Tbuf, NN, nullptr, nullptr);
  gemm64<0, 0, 0><<<dim3(32, 32), 256, 0, stream>>>(NN, NN, NN, Tbuf, NN, o_c, NN,
                                                    o_acoarse, NN, nullptr, nullptr);
}